// Round 12
// baseline (224.495 us; speedup 1.0000x reference)
//
#include <hip/hip_runtime.h>
#include <hip/hip_bf16.h>

typedef __attribute__((ext_vector_type(8))) short short8;
typedef __attribute__((ext_vector_type(4))) float f32x4;

#define NNODES 8192
#define FDIM 128

// ---------------- helpers ----------------
static __device__ inline unsigned short f2bf(float f) {
    union { float f; unsigned int u; } a; a.f = f;
    unsigned int u = a.u;
    unsigned int r = u + 0x7FFFu + ((u >> 16) & 1u);
    return (unsigned short)(r >> 16);
}

// ---------------- zero ints ----------------
__global__ void k_zero(int* __restrict__ p, int n) {
    int i = blockIdx.x * blockDim.x + threadIdx.x;
    if (i < n) p[i] = 0;
}

// ---------------- degree count (cnt_s | cnt_d in one array) ----------------
__global__ void k_deg_int(const int* __restrict__ src, const int* __restrict__ dst,
                          int* __restrict__ cnt, int E) {
    int e = blockIdx.x * blockDim.x + threadIdx.x;
    if (e < E) {
        atomicAdd(&cnt[src[e]], 1);
        atomicAdd(&cnt[NNODES + dst[e]], 1);
    }
}

// ---------------- single-block: norm_s + exclusive scan over cnt_d ----------------
__global__ __launch_bounds__(256) void k_scan_norms(const int* __restrict__ cnt,
                                                    float* __restrict__ norm_s,
                                                    int* __restrict__ row_start,
                                                    int* __restrict__ cursor, int n) {
    __shared__ int partial[256];
    __shared__ int offs[257];
    int t = threadIdx.x;
    int base = t * 32;
    const int* cnt_d = cnt + NNODES;
#pragma unroll
    for (int i = 0; i < 32; ++i)
        norm_s[base + i] = rsqrtf(fmaxf((float)cnt[base + i], 1.0f));
    int local[32];
    int s = 0;
#pragma unroll
    for (int i = 0; i < 32; ++i) { local[i] = s; s += cnt_d[base + i]; }
    partial[t] = s;
    __syncthreads();
    if (t == 0) {
        int acc = 0;
        for (int i = 0; i < 256; ++i) { offs[i] = acc; acc += partial[i]; }
        offs[256] = acc;
    }
    __syncthreads();
    int o = offs[t];
#pragma unroll
    for (int i = 0; i < 32; ++i) {
        int v = o + local[i];
        row_start[base + i] = v;
        cursor[base + i] = v;
    }
    if (t == 0) row_start[n] = offs[256];
}

// ---------------- merged: CSR fill (blocks < fillB) + linear1 (rest) ----------------
__global__ __launch_bounds__(256) void k_fill_lin(const int* __restrict__ src,
                                                  const int* __restrict__ dst,
                                                  int* __restrict__ cursor,
                                                  int* __restrict__ csr_src, int E, int fillB,
                                                  const float* __restrict__ X,
                                                  const float* __restrict__ W,
                                                  const float* __restrict__ norm,
                                                  float* __restrict__ Y) {
    constexpr int K = 256;
    __shared__ float xs[16][K];
    const int t = threadIdx.x;
    if (blockIdx.x < fillB) {
        int e = blockIdx.x * 256 + t;
        if (e < E) {
            int pos = atomicAdd(&cursor[dst[e]], 1);
            csr_src[pos] = src[e];
        }
        return;
    }
    // linear1: y1[row] = (x[row] @ W1) * norm_s[row]
    int row0 = (blockIdx.x - fillB) * 16;
    constexpr int K4 = K / 4;
    constexpr int NCH = 16 * K4 / 256;
#pragma unroll
    for (int i = 0; i < NCH; ++i) {
        int c = t + i * 256;
        int r = c / K4, k4 = c % K4;
        *(float4*)&xs[r][k4 * 4] = *(const float4*)(X + (size_t)(row0 + r) * K + k4 * 4);
    }
    __syncthreads();
    int lane = t & 31, g = t >> 5;
    int r0 = g * 2, r1 = r0 + 1;
    int c = lane * 4;
    f32x4 acc0 = {0.f, 0.f, 0.f, 0.f}, acc1 = {0.f, 0.f, 0.f, 0.f};
    for (int k = 0; k < K; k += 4) {
        f32x4 x0 = *(f32x4*)&xs[r0][k];
        f32x4 x1 = *(f32x4*)&xs[r1][k];
#pragma unroll
        for (int kk = 0; kk < 4; ++kk) {
            f32x4 w = *(const f32x4*)(W + (size_t)(k + kk) * FDIM + c);
            acc0 += w * x0[kk];
            acc1 += w * x1[kk];
        }
    }
    float n0 = norm[row0 + r0], n1 = norm[row0 + r1];
    *(f32x4*)(Y + (size_t)(row0 + r0) * FDIM + c) = acc0 * n0;
    *(f32x4*)(Y + (size_t)(row0 + r1) * FDIM + c) = acc1 * n1;
}

// ---------------- fused gather1 + linear2 ----------------
__global__ __launch_bounds__(256) void k_gatlin(const float* __restrict__ Y,
                                                const int* __restrict__ row_start,
                                                const int* __restrict__ csr_src,
                                                const float* __restrict__ b1,
                                                const float* __restrict__ W2,
                                                const float* __restrict__ norm_s,
                                                float* __restrict__ Y2) {
    __shared__ float h1s[8][132];  // +4 pad
    const int t = threadIdx.x;
    const int g = t >> 5, lane = t & 31;
    const int node = blockIdx.x * 8 + g;
    const int c4 = lane << 2;

    int beg = row_start[node], end = row_start[node + 1];
    f32x4 acc0 = {0.f, 0.f, 0.f, 0.f}, acc1 = {0.f, 0.f, 0.f, 0.f};
    int e = beg;
    for (; e + 3 < end; e += 4) {
        int s0 = csr_src[e], s1 = csr_src[e + 1], s2 = csr_src[e + 2], s3 = csr_src[e + 3];
        f32x4 v0 = *(const f32x4*)(Y + ((size_t)s0 << 7) + c4);
        f32x4 v1 = *(const f32x4*)(Y + ((size_t)s1 << 7) + c4);
        f32x4 v2 = *(const f32x4*)(Y + ((size_t)s2 << 7) + c4);
        f32x4 v3 = *(const f32x4*)(Y + ((size_t)s3 << 7) + c4);
        acc0 += v0; acc1 += v1; acc0 += v2; acc1 += v3;
    }
    for (; e < end; ++e) {
        int s0 = csr_src[e];
        acc0 += *(const f32x4*)(Y + ((size_t)s0 << 7) + c4);
    }
    f32x4 acc = acc0 + acc1;
    float scale = rsqrtf(fmaxf((float)(end - beg), 1.0f));
    f32x4 b = *(const f32x4*)(b1 + c4);
    f32x4 v = acc * scale + b;
#pragma unroll
    for (int i = 0; i < 4; ++i) v[i] = fmaxf(v[i], 0.f);
    *(f32x4*)&h1s[g][c4] = v;
    __syncthreads();

    f32x4 acc2 = {0.f, 0.f, 0.f, 0.f};
    for (int k = 0; k < FDIM; k += 4) {
        f32x4 xv = *(f32x4*)&h1s[g][k];
#pragma unroll
        for (int kk = 0; kk < 4; ++kk) {
            f32x4 w = *(const f32x4*)(W2 + (size_t)(k + kk) * FDIM + c4);
            acc2 += w * xv[kk];
        }
    }
    float ns = norm_s[node];
    *(f32x4*)(Y2 + ((size_t)node << 7) + c4) = acc2 * ns;
}

// ---------------- gather2: h2 = bf16( gather(y2)*nd + b2 ) ----------------
__global__ __launch_bounds__(256) void k_gat2(const float* __restrict__ Y,
                                              const int* __restrict__ row_start,
                                              const int* __restrict__ csr_src,
                                              const float* __restrict__ bias,
                                              unsigned short* __restrict__ outp) {
    int t = threadIdx.x;
    int node = blockIdx.x * 8 + (t >> 5);
    int c4 = (t & 31) << 2;
    int beg = row_start[node], end = row_start[node + 1];
    f32x4 acc0 = {0.f, 0.f, 0.f, 0.f}, acc1 = {0.f, 0.f, 0.f, 0.f};
    int e = beg;
    for (; e + 3 < end; e += 4) {
        int s0 = csr_src[e], s1 = csr_src[e + 1], s2 = csr_src[e + 2], s3 = csr_src[e + 3];
        f32x4 v0 = *(const f32x4*)(Y + ((size_t)s0 << 7) + c4);
        f32x4 v1 = *(const f32x4*)(Y + ((size_t)s1 << 7) + c4);
        f32x4 v2 = *(const f32x4*)(Y + ((size_t)s2 << 7) + c4);
        f32x4 v3 = *(const f32x4*)(Y + ((size_t)s3 << 7) + c4);
        acc0 += v0; acc1 += v1; acc0 += v2; acc1 += v3;
    }
    for (; e < end; ++e) {
        int s0 = csr_src[e];
        acc0 += *(const f32x4*)(Y + ((size_t)s0 << 7) + c4);
    }
    f32x4 acc = acc0 + acc1;
    float scale = rsqrtf(fmaxf((float)(end - beg), 1.0f));
    f32x4 b = *(const f32x4*)(bias + c4);
    f32x4 v = acc * scale + b;
    ushort4 u;
    u.x = f2bf(v[0]); u.y = f2bf(v[1]); u.z = f2bf(v[2]); u.w = f2bf(v[3]);
    *(ushort4*)(outp + ((size_t)node << 7) + c4) = u;
}

// ---------------- decode: C = sigmoid(H @ H^T), H is [8192][128] bf16 ----------------
// LDS-staged (r10-proven; r11 showed direct-global is -28us worse), swapped-operand
// MFMA -> float4 stores, rcp sigmoid. NEW: nontemporal C stores so the 268MB
// write stream doesn't evict the L2-resident H between tiles.
__global__ __launch_bounds__(256) void k_decode(const __hip_bfloat16* __restrict__ H,
                                                float* __restrict__ C) {
    __shared__ __align__(16) unsigned char smem[65536];
    unsigned char* sA = smem;
    unsigned char* sB = smem + 32768;
    const int ti = blockIdx.x, tj = blockIdx.y;
    const int t = threadIdx.x;
    const unsigned char* gH = (const unsigned char*)H;

#pragma unroll
    for (int i = 0; i < 8; ++i) {
        int chunk = t + i * 256;
        int row = chunk >> 4;
        int cc = (chunk & 15) << 4;
        int lofs = row * 256 + (cc ^ ((row & 7) << 4));
        *(float4*)(sA + lofs) = *(const float4*)(gH + ((size_t)(ti * 128 + row) << 8) + cc);
        *(float4*)(sB + lofs) = *(const float4*)(gH + ((size_t)(tj * 128 + row) << 8) + cc);
    }
    __syncthreads();

    const int w = t >> 6, lane = t & 63;
    const int wr = (w >> 1) * 64, wc = (w & 1) * 64;
    const int lr = lane & 15;
    const int lk = (lane >> 4) * 16;

    f32x4 acc[4][4] = {};

#pragma unroll
    for (int ks = 0; ks < 4; ++ks) {
        short8 af[4], bfr[4];
#pragma unroll
        for (int mi = 0; mi < 4; ++mi) {
            int row = wr + mi * 16 + lr;
            int off = row * 256 + ((ks * 64 + lk) ^ ((row & 7) << 4));
            af[mi] = *(const short8*)(sA + off);
        }
#pragma unroll
        for (int ni = 0; ni < 4; ++ni) {
            int row = wc + ni * 16 + lr;
            int off = row * 256 + ((ks * 64 + lk) ^ ((row & 7) << 4));
            bfr[ni] = *(const short8*)(sB + off);
        }
        // swapped operands: lane-regs hold 4 consecutive cols of one row
#pragma unroll
        for (int mi = 0; mi < 4; ++mi)
#pragma unroll
            for (int ni = 0; ni < 4; ++ni)
                acc[mi][ni] = __builtin_amdgcn_mfma_f32_16x16x32_bf16(bfr[ni], af[mi],
                                                                      acc[mi][ni], 0, 0, 0);
    }

    // lane holds: row = ti*128 + wr + mi*16 + (lane&15)
    //             cols = tj*128 + wc + ni*16 + (lane>>4)*4 + {0..3}
    const int qrow = lane & 15;
    const int pcolb = (lane >> 4) * 4;
#pragma unroll
    for (int mi = 0; mi < 4; ++mi) {
        size_t rowoff = (size_t)(ti * 128 + wr + mi * 16 + qrow) * NNODES;
#pragma unroll
        for (int ni = 0; ni < 4; ++ni) {
            int colb = tj * 128 + wc + ni * 16 + pcolb;
            f32x4 s;
#pragma unroll
            for (int r = 0; r < 4; ++r)
                s[r] = __builtin_amdgcn_rcpf(1.0f + __expf(-acc[mi][ni][r]));
            __builtin_nontemporal_store(s, (f32x4*)(C + rowoff + colb));
        }
    }
}

extern "C" void kernel_launch(void* const* d_in, const int* in_sizes, int n_in,
                              void* d_out, int out_size, void* d_ws, size_t ws_size,
                              hipStream_t stream) {
    const float* x  = (const float*)d_in[0];
    const int* src  = (const int*)d_in[1];
    const int* dst  = (const int*)d_in[2];
    const float* W1 = (const float*)d_in[3];
    const float* b1 = (const float*)d_in[4];
    const float* W2 = (const float*)d_in[5];
    const float* b2 = (const float*)d_in[6];
    float* out = (float*)d_out;
    const int E = in_sizes[1];

    char* ws = (char*)d_ws;
    float* norm_s    = (float*)(ws + 0);                // 32KB
    int*   cnt       = (int*)(ws + (32 << 10));         // 64KB (cnt_s | cnt_d)
    int*   row_start = (int*)(ws + (96 << 10));         // 8193 ints
    int*   cursor    = (int*)(ws + (132 << 10));        // 32KB
    int*   csr_src   = (int*)(ws + (164 << 10));        // E ints = 1MB
    char*  big       = ws + (164 << 10) + ((size_t)E * 4);
    float* bufA      = (float*)big;                     // 4MB (y1)
    float* bufB      = (float*)(big + (4 << 20));       // 4MB (y2)
    __hip_bfloat16* h2bf = (__hip_bfloat16*)(big + (8 << 20));  // 2MB

    // zero degree counters (kernel, not memset — in-graph fill nodes are slow)
    k_zero<<<64, 256, 0, stream>>>(cnt, 2 * NNODES);

    // degrees, then norms + scan (single block)
    k_deg_int<<<(E + 255) / 256, 256, 0, stream>>>(src, dst, cnt, E);
    k_scan_norms<<<1, 256, 0, stream>>>(cnt, norm_s, row_start, cursor, NNODES);

    // merged: CSR fill (1024 blocks) + linear1 (512 blocks)
    const int fillB = (E + 255) / 256;
    k_fill_lin<<<fillB + NNODES / 16, 256, 0, stream>>>(src, dst, cursor, csr_src, E, fillB,
                                                        x, W1, norm_s, bufA);

    // fused: h1 = relu(gather(y1)*nd + b1) [LDS-local]; y2 = (h1@W2)*ns
    k_gatlin<<<NNODES / 8, 256, 0, stream>>>(bufA, row_start, csr_src, b1, W2, norm_s, bufB);
    // layer 2 gather: h2 = gather(y2)*nd + b2 -> bf16
    k_gat2<<<NNODES / 8, 256, 0, stream>>>(bufB, row_start, csr_src, b2, (unsigned short*)h2bf);

    // decode: out = sigmoid(h2 @ h2^T), LDS-staged, nontemporal C stores
    k_decode<<<dim3(64, 64), 256, 0, stream>>>(h2bf, out);
}

// Round 13
// 184.898 us; speedup vs baseline: 1.2142x; 1.2142x over previous
//
#include <hip/hip_runtime.h>
#include <hip/hip_bf16.h>

typedef __attribute__((ext_vector_type(8))) short short8;
typedef __attribute__((ext_vector_type(4))) float f32x4;

#define NNODES 8192
#define FDIM 128

// ---------------- helpers ----------------
static __device__ inline unsigned short f2bf(float f) {
    union { float f; unsigned int u; } a; a.f = f;
    unsigned int u = a.u;
    unsigned int r = u + 0x7FFFu + ((u >> 16) & 1u);
    return (unsigned short)(r >> 16);
}

// ---------------- zero ints ----------------
__global__ void k_zero(int* __restrict__ p, int n) {
    int i = blockIdx.x * blockDim.x + threadIdx.x;
    if (i < n) p[i] = 0;
}

// ---------------- degree count (cnt_s | cnt_d in one array) ----------------
__global__ void k_deg_int(const int* __restrict__ src, const int* __restrict__ dst,
                          int* __restrict__ cnt, int E) {
    int e = blockIdx.x * blockDim.x + threadIdx.x;
    if (e < E) {
        atomicAdd(&cnt[src[e]], 1);
        atomicAdd(&cnt[NNODES + dst[e]], 1);
    }
}

// ---------------- single-block: norm_s + exclusive scan over cnt_d ----------------
__global__ __launch_bounds__(256) void k_scan_norms(const int* __restrict__ cnt,
                                                    float* __restrict__ norm_s,
                                                    int* __restrict__ row_start,
                                                    int* __restrict__ cursor, int n) {
    __shared__ int partial[256];
    __shared__ int offs[257];
    int t = threadIdx.x;
    int base = t * 32;
    const int* cnt_d = cnt + NNODES;
#pragma unroll
    for (int i = 0; i < 32; ++i)
        norm_s[base + i] = rsqrtf(fmaxf((float)cnt[base + i], 1.0f));
    int local[32];
    int s = 0;
#pragma unroll
    for (int i = 0; i < 32; ++i) { local[i] = s; s += cnt_d[base + i]; }
    partial[t] = s;
    __syncthreads();
    if (t == 0) {
        int acc = 0;
        for (int i = 0; i < 256; ++i) { offs[i] = acc; acc += partial[i]; }
        offs[256] = acc;
    }
    __syncthreads();
    int o = offs[t];
#pragma unroll
    for (int i = 0; i < 32; ++i) {
        int v = o + local[i];
        row_start[base + i] = v;
        cursor[base + i] = v;
    }
    if (t == 0) row_start[n] = offs[256];
}

// ---------------- merged: CSR fill (blocks < fillB) + linear1 (rest) ----------------
__global__ __launch_bounds__(256) void k_fill_lin(const int* __restrict__ src,
                                                  const int* __restrict__ dst,
                                                  int* __restrict__ cursor,
                                                  int* __restrict__ csr_src, int E, int fillB,
                                                  const float* __restrict__ X,
                                                  const float* __restrict__ W,
                                                  const float* __restrict__ norm,
                                                  float* __restrict__ Y) {
    constexpr int K = 256;
    __shared__ float xs[16][K];
    const int t = threadIdx.x;
    if (blockIdx.x < fillB) {
        int e = blockIdx.x * 256 + t;
        if (e < E) {
            int pos = atomicAdd(&cursor[dst[e]], 1);
            csr_src[pos] = src[e];
        }
        return;
    }
    // linear1: y1[row] = (x[row] @ W1) * norm_s[row]
    int row0 = (blockIdx.x - fillB) * 16;
    constexpr int K4 = K / 4;
    constexpr int NCH = 16 * K4 / 256;
#pragma unroll
    for (int i = 0; i < NCH; ++i) {
        int c = t + i * 256;
        int r = c / K4, k4 = c % K4;
        *(float4*)&xs[r][k4 * 4] = *(const float4*)(X + (size_t)(row0 + r) * K + k4 * 4);
    }
    __syncthreads();
    int lane = t & 31, g = t >> 5;
    int r0 = g * 2, r1 = r0 + 1;
    int c = lane * 4;
    f32x4 acc0 = {0.f, 0.f, 0.f, 0.f}, acc1 = {0.f, 0.f, 0.f, 0.f};
    for (int k = 0; k < K; k += 4) {
        f32x4 x0 = *(f32x4*)&xs[r0][k];
        f32x4 x1 = *(f32x4*)&xs[r1][k];
#pragma unroll
        for (int kk = 0; kk < 4; ++kk) {
            f32x4 w = *(const f32x4*)(W + (size_t)(k + kk) * FDIM + c);
            acc0 += w * x0[kk];
            acc1 += w * x1[kk];
        }
    }
    float n0 = norm[row0 + r0], n1 = norm[row0 + r1];
    *(f32x4*)(Y + (size_t)(row0 + r0) * FDIM + c) = acc0 * n0;
    *(f32x4*)(Y + (size_t)(row0 + r1) * FDIM + c) = acc1 * n1;
}

// ---------------- fused gather1 + linear2 ----------------
__global__ __launch_bounds__(256) void k_gatlin(const float* __restrict__ Y,
                                                const int* __restrict__ row_start,
                                                const int* __restrict__ csr_src,
                                                const float* __restrict__ b1,
                                                const float* __restrict__ W2,
                                                const float* __restrict__ norm_s,
                                                float* __restrict__ Y2) {
    __shared__ float h1s[8][132];  // +4 pad
    const int t = threadIdx.x;
    const int g = t >> 5, lane = t & 31;
    const int node = blockIdx.x * 8 + g;
    const int c4 = lane << 2;

    int beg = row_start[node], end = row_start[node + 1];
    f32x4 acc0 = {0.f, 0.f, 0.f, 0.f}, acc1 = {0.f, 0.f, 0.f, 0.f};
    int e = beg;
    for (; e + 3 < end; e += 4) {
        int s0 = csr_src[e], s1 = csr_src[e + 1], s2 = csr_src[e + 2], s3 = csr_src[e + 3];
        f32x4 v0 = *(const f32x4*)(Y + ((size_t)s0 << 7) + c4);
        f32x4 v1 = *(const f32x4*)(Y + ((size_t)s1 << 7) + c4);
        f32x4 v2 = *(const f32x4*)(Y + ((size_t)s2 << 7) + c4);
        f32x4 v3 = *(const f32x4*)(Y + ((size_t)s3 << 7) + c4);
        acc0 += v0; acc1 += v1; acc0 += v2; acc1 += v3;
    }
    for (; e < end; ++e) {
        int s0 = csr_src[e];
        acc0 += *(const f32x4*)(Y + ((size_t)s0 << 7) + c4);
    }
    f32x4 acc = acc0 + acc1;
    float scale = rsqrtf(fmaxf((float)(end - beg), 1.0f));
    f32x4 b = *(const f32x4*)(b1 + c4);
    f32x4 v = acc * scale + b;
#pragma unroll
    for (int i = 0; i < 4; ++i) v[i] = fmaxf(v[i], 0.f);
    *(f32x4*)&h1s[g][c4] = v;
    __syncthreads();

    f32x4 acc2 = {0.f, 0.f, 0.f, 0.f};
    for (int k = 0; k < FDIM; k += 4) {
        f32x4 xv = *(f32x4*)&h1s[g][k];
#pragma unroll
        for (int kk = 0; kk < 4; ++kk) {
            f32x4 w = *(const f32x4*)(W2 + (size_t)(k + kk) * FDIM + c4);
            acc2 += w * xv[kk];
        }
    }
    float ns = norm_s[node];
    *(f32x4*)(Y2 + ((size_t)node << 7) + c4) = acc2 * ns;
}

// ---------------- gather2: h2 = bf16( gather(y2)*nd + b2 ) ----------------
__global__ __launch_bounds__(256) void k_gat2(const float* __restrict__ Y,
                                              const int* __restrict__ row_start,
                                              const int* __restrict__ csr_src,
                                              const float* __restrict__ bias,
                                              unsigned short* __restrict__ outp) {
    int t = threadIdx.x;
    int node = blockIdx.x * 8 + (t >> 5);
    int c4 = (t & 31) << 2;
    int beg = row_start[node], end = row_start[node + 1];
    f32x4 acc0 = {0.f, 0.f, 0.f, 0.f}, acc1 = {0.f, 0.f, 0.f, 0.f};
    int e = beg;
    for (; e + 3 < end; e += 4) {
        int s0 = csr_src[e], s1 = csr_src[e + 1], s2 = csr_src[e + 2], s3 = csr_src[e + 3];
        f32x4 v0 = *(const f32x4*)(Y + ((size_t)s0 << 7) + c4);
        f32x4 v1 = *(const f32x4*)(Y + ((size_t)s1 << 7) + c4);
        f32x4 v2 = *(const f32x4*)(Y + ((size_t)s2 << 7) + c4);
        f32x4 v3 = *(const f32x4*)(Y + ((size_t)s3 << 7) + c4);
        acc0 += v0; acc1 += v1; acc0 += v2; acc1 += v3;
    }
    for (; e < end; ++e) {
        int s0 = csr_src[e];
        acc0 += *(const f32x4*)(Y + ((size_t)s0 << 7) + c4);
    }
    f32x4 acc = acc0 + acc1;
    float scale = rsqrtf(fmaxf((float)(end - beg), 1.0f));
    f32x4 b = *(const f32x4*)(bias + c4);
    f32x4 v = acc * scale + b;
    ushort4 u;
    u.x = f2bf(v[0]); u.y = f2bf(v[1]); u.z = f2bf(v[2]); u.w = f2bf(v[3]);
    *(ushort4*)(outp + ((size_t)node << 7) + c4) = u;
}

// ---------------- decode: C = sigmoid(H @ H^T), H is [8192][128] bf16 ----------------
// LDS-staged input (r10-proven), swapped-operand MFMA, rcp sigmoid.
// NEW: LDS-transposed epilogue — fragments land in tileT[128][128] (reusing the
// 64KB staging LDS, XOR-swizzled), then each wave streams out 2 complete 512B
// rows per instr (vs 16 scattered 64B runs) for HBM write-combine efficiency.
// Plain stores (nontemporal proved -45us in r12).
__global__ __launch_bounds__(256) void k_decode(const __hip_bfloat16* __restrict__ H,
                                                float* __restrict__ C) {
    __shared__ __align__(16) unsigned char smem[65536];
    unsigned char* sA = smem;
    unsigned char* sB = smem + 32768;
    const int ti = blockIdx.x, tj = blockIdx.y;
    const int t = threadIdx.x;
    const unsigned char* gH = (const unsigned char*)H;

#pragma unroll
    for (int i = 0; i < 8; ++i) {
        int chunk = t + i * 256;
        int row = chunk >> 4;
        int cc = (chunk & 15) << 4;
        int lofs = row * 256 + (cc ^ ((row & 7) << 4));
        *(float4*)(sA + lofs) = *(const float4*)(gH + ((size_t)(ti * 128 + row) << 8) + cc);
        *(float4*)(sB + lofs) = *(const float4*)(gH + ((size_t)(tj * 128 + row) << 8) + cc);
    }
    __syncthreads();

    const int w = t >> 6, lane = t & 63;
    const int wr = (w >> 1) * 64, wc = (w & 1) * 64;
    const int lr = lane & 15;
    const int lk = (lane >> 4) * 16;

    f32x4 acc[4][4] = {};

#pragma unroll
    for (int ks = 0; ks < 4; ++ks) {
        short8 af[4], bfr[4];
#pragma unroll
        for (int mi = 0; mi < 4; ++mi) {
            int row = wr + mi * 16 + lr;
            int off = row * 256 + ((ks * 64 + lk) ^ ((row & 7) << 4));
            af[mi] = *(const short8*)(sA + off);
        }
#pragma unroll
        for (int ni = 0; ni < 4; ++ni) {
            int row = wc + ni * 16 + lr;
            int off = row * 256 + ((ks * 64 + lk) ^ ((row & 7) << 4));
            bfr[ni] = *(const short8*)(sB + off);
        }
        // swapped operands: lane-regs hold 4 consecutive cols of one row
#pragma unroll
        for (int mi = 0; mi < 4; ++mi)
#pragma unroll
            for (int ni = 0; ni < 4; ++ni)
                acc[mi][ni] = __builtin_amdgcn_mfma_f32_16x16x32_bf16(bfr[ni], af[mi],
                                                                      acc[mi][ni], 0, 0, 0);
    }

    // sigmoid in-register, then transpose-collect in LDS (reuse staging buffer)
    __syncthreads();  // all K-loop LDS reads complete before overwrite
    float* tileT = (float*)smem;
    const int qrow = lane & 15;
    const int pcolb = (lane >> 4) * 4;
#pragma unroll
    for (int mi = 0; mi < 4; ++mi) {
        int row = wr + mi * 16 + qrow;
#pragma unroll
        for (int ni = 0; ni < 4; ++ni) {
            int col = wc + ni * 16 + pcolb;
            f32x4 s;
#pragma unroll
            for (int r = 0; r < 4; ++r)
                s[r] = __builtin_amdgcn_rcpf(1.0f + __expf(-acc[mi][ni][r]));
            // swizzle: 16 lanes/colgroup hit 8 bank-quads (2-way = free, m136)
            *(f32x4*)(tileT + row * 128 + (col ^ ((row & 7) << 2))) = s;
        }
    }
    __syncthreads();

    // stream out: each wave writes 2 complete rows (2 x 512B contiguous runs)
    const float* Cbase_src = tileT;
    float* Crow0 = C + (size_t)(ti * 128) * NNODES + tj * 128;
#pragma unroll
    for (int i = 0; i < 16; ++i) {
        int chunk = i * 256 + t;
        int mr = chunk >> 5;            // row 0..127
        int mc4 = (chunk & 31) << 2;    // col group 0..124
        f32x4 v = *(const f32x4*)(Cbase_src + mr * 128 + (mc4 ^ ((mr & 7) << 2)));
        *(f32x4*)(Crow0 + (size_t)mr * NNODES + mc4) = v;
    }
}

extern "C" void kernel_launch(void* const* d_in, const int* in_sizes, int n_in,
                              void* d_out, int out_size, void* d_ws, size_t ws_size,
                              hipStream_t stream) {
    const float* x  = (const float*)d_in[0];
    const int* src  = (const int*)d_in[1];
    const int* dst  = (const int*)d_in[2];
    const float* W1 = (const float*)d_in[3];
    const float* b1 = (const float*)d_in[4];
    const float* W2 = (const float*)d_in[5];
    const float* b2 = (const float*)d_in[6];
    float* out = (float*)d_out;
    const int E = in_sizes[1];

    char* ws = (char*)d_ws;
    float* norm_s    = (float*)(ws + 0);                // 32KB
    int*   cnt       = (int*)(ws + (32 << 10));         // 64KB (cnt_s | cnt_d)
    int*   row_start = (int*)(ws + (96 << 10));         // 8193 ints
    int*   cursor    = (int*)(ws + (132 << 10));        // 32KB
    int*   csr_src   = (int*)(ws + (164 << 10));        // E ints = 1MB
    char*  big       = ws + (164 << 10) + ((size_t)E * 4);
    float* bufA      = (float*)big;                     // 4MB (y1)
    float* bufB      = (float*)(big + (4 << 20));       // 4MB (y2)
    __hip_bfloat16* h2bf = (__hip_bfloat16*)(big + (8 << 20));  // 2MB

    // zero degree counters (kernel, not memset — in-graph fill nodes are slow)
    k_zero<<<64, 256, 0, stream>>>(cnt, 2 * NNODES);

    // degrees, then norms + scan (single block)
    k_deg_int<<<(E + 255) / 256, 256, 0, stream>>>(src, dst, cnt, E);
    k_scan_norms<<<1, 256, 0, stream>>>(cnt, norm_s, row_start, cursor, NNODES);

    // merged: CSR fill (1024 blocks) + linear1 (512 blocks)
    const int fillB = (E + 255) / 256;
    k_fill_lin<<<fillB + NNODES / 16, 256, 0, stream>>>(src, dst, cursor, csr_src, E, fillB,
                                                        x, W1, norm_s, bufA);

    // fused: h1 = relu(gather(y1)*nd + b1) [LDS-local]; y2 = (h1@W2)*ns
    k_gatlin<<<NNODES / 8, 256, 0, stream>>>(bufA, row_start, csr_src, b1, W2, norm_s, bufB);
    // layer 2 gather: h2 = gather(y2)*nd + b2 -> bf16
    k_gat2<<<NNODES / 8, 256, 0, stream>>>(bufB, row_start, csr_src, b2, (unsigned short*)h2bf);

    // decode: out = sigmoid(h2 @ h2^T), LDS-staged, row-coalesced epilogue
    k_decode<<<dim3(64, 64), 256, 0, stream>>>(h2bf, out);
}

// Round 14
// 178.839 us; speedup vs baseline: 1.2553x; 1.0339x over previous
//
#include <hip/hip_runtime.h>
#include <hip/hip_bf16.h>

typedef __attribute__((ext_vector_type(8))) short short8;
typedef __attribute__((ext_vector_type(4))) float f32x4;

#define NNODES 8192
#define FDIM 128

// ---------------- helpers ----------------
static __device__ inline unsigned short f2bf(float f) {
    union { float f; unsigned int u; } a; a.f = f;
    unsigned int u = a.u;
    unsigned int r = u + 0x7FFFu + ((u >> 16) & 1u);
    return (unsigned short)(r >> 16);
}

// ---------------- zero ints ----------------
__global__ void k_zero(int* __restrict__ p, int n) {
    int i = blockIdx.x * blockDim.x + threadIdx.x;
    if (i < n) p[i] = 0;
}

// ---------------- degree count (cnt_s | cnt_d in one array) ----------------
__global__ void k_deg_int(const int* __restrict__ src, const int* __restrict__ dst,
                          int* __restrict__ cnt, int E) {
    int e = blockIdx.x * blockDim.x + threadIdx.x;
    if (e < E) {
        atomicAdd(&cnt[src[e]], 1);
        atomicAdd(&cnt[NNODES + dst[e]], 1);
    }
}

// ---------------- single-block: norm_s + exclusive scan over cnt_d ----------------
__global__ __launch_bounds__(256) void k_scan_norms(const int* __restrict__ cnt,
                                                    float* __restrict__ norm_s,
                                                    int* __restrict__ row_start,
                                                    int* __restrict__ cursor, int n) {
    __shared__ int partial[256];
    __shared__ int offs[257];
    int t = threadIdx.x;
    int base = t * 32;
    const int* cnt_d = cnt + NNODES;
#pragma unroll
    for (int i = 0; i < 32; ++i)
        norm_s[base + i] = rsqrtf(fmaxf((float)cnt[base + i], 1.0f));
    int local[32];
    int s = 0;
#pragma unroll
    for (int i = 0; i < 32; ++i) { local[i] = s; s += cnt_d[base + i]; }
    partial[t] = s;
    __syncthreads();
    if (t == 0) {
        int acc = 0;
        for (int i = 0; i < 256; ++i) { offs[i] = acc; acc += partial[i]; }
        offs[256] = acc;
    }
    __syncthreads();
    int o = offs[t];
#pragma unroll
    for (int i = 0; i < 32; ++i) {
        int v = o + local[i];
        row_start[base + i] = v;
        cursor[base + i] = v;
    }
    if (t == 0) row_start[n] = offs[256];
}

// ---------------- merged: CSR fill (blocks < fillB) + linear1 (rest) ----------------
__global__ __launch_bounds__(256) void k_fill_lin(const int* __restrict__ src,
                                                  const int* __restrict__ dst,
                                                  int* __restrict__ cursor,
                                                  int* __restrict__ csr_src, int E, int fillB,
                                                  const float* __restrict__ X,
                                                  const float* __restrict__ W,
                                                  const float* __restrict__ norm,
                                                  float* __restrict__ Y) {
    constexpr int K = 256;
    __shared__ float xs[16][K];
    const int t = threadIdx.x;
    if (blockIdx.x < fillB) {
        int e = blockIdx.x * 256 + t;
        if (e < E) {
            int pos = atomicAdd(&cursor[dst[e]], 1);
            csr_src[pos] = src[e];
        }
        return;
    }
    // linear1: y1[row] = (x[row] @ W1) * norm_s[row]
    int row0 = (blockIdx.x - fillB) * 16;
    constexpr int K4 = K / 4;
    constexpr int NCH = 16 * K4 / 256;
#pragma unroll
    for (int i = 0; i < NCH; ++i) {
        int c = t + i * 256;
        int r = c / K4, k4 = c % K4;
        *(float4*)&xs[r][k4 * 4] = *(const float4*)(X + (size_t)(row0 + r) * K + k4 * 4);
    }
    __syncthreads();
    int lane = t & 31, g = t >> 5;
    int r0 = g * 2, r1 = r0 + 1;
    int c = lane * 4;
    f32x4 acc0 = {0.f, 0.f, 0.f, 0.f}, acc1 = {0.f, 0.f, 0.f, 0.f};
    for (int k = 0; k < K; k += 4) {
        f32x4 x0 = *(f32x4*)&xs[r0][k];
        f32x4 x1 = *(f32x4*)&xs[r1][k];
#pragma unroll
        for (int kk = 0; kk < 4; ++kk) {
            f32x4 w = *(const f32x4*)(W + (size_t)(k + kk) * FDIM + c);
            acc0 += w * x0[kk];
            acc1 += w * x1[kk];
        }
    }
    float n0 = norm[row0 + r0], n1 = norm[row0 + r1];
    *(f32x4*)(Y + (size_t)(row0 + r0) * FDIM + c) = acc0 * n0;
    *(f32x4*)(Y + (size_t)(row0 + r1) * FDIM + c) = acc1 * n1;
}

// ---------------- fused gather1 + linear2 ----------------
__global__ __launch_bounds__(256) void k_gatlin(const float* __restrict__ Y,
                                                const int* __restrict__ row_start,
                                                const int* __restrict__ csr_src,
                                                const float* __restrict__ b1,
                                                const float* __restrict__ W2,
                                                const float* __restrict__ norm_s,
                                                float* __restrict__ Y2) {
    __shared__ float h1s[8][132];  // +4 pad
    const int t = threadIdx.x;
    const int g = t >> 5, lane = t & 31;
    const int node = blockIdx.x * 8 + g;
    const int c4 = lane << 2;

    int beg = row_start[node], end = row_start[node + 1];
    f32x4 acc0 = {0.f, 0.f, 0.f, 0.f}, acc1 = {0.f, 0.f, 0.f, 0.f};
    int e = beg;
    for (; e + 3 < end; e += 4) {
        int s0 = csr_src[e], s1 = csr_src[e + 1], s2 = csr_src[e + 2], s3 = csr_src[e + 3];
        f32x4 v0 = *(const f32x4*)(Y + ((size_t)s0 << 7) + c4);
        f32x4 v1 = *(const f32x4*)(Y + ((size_t)s1 << 7) + c4);
        f32x4 v2 = *(const f32x4*)(Y + ((size_t)s2 << 7) + c4);
        f32x4 v3 = *(const f32x4*)(Y + ((size_t)s3 << 7) + c4);
        acc0 += v0; acc1 += v1; acc0 += v2; acc1 += v3;
    }
    for (; e < end; ++e) {
        int s0 = csr_src[e];
        acc0 += *(const f32x4*)(Y + ((size_t)s0 << 7) + c4);
    }
    f32x4 acc = acc0 + acc1;
    float scale = rsqrtf(fmaxf((float)(end - beg), 1.0f));
    f32x4 b = *(const f32x4*)(b1 + c4);
    f32x4 v = acc * scale + b;
#pragma unroll
    for (int i = 0; i < 4; ++i) v[i] = fmaxf(v[i], 0.f);
    *(f32x4*)&h1s[g][c4] = v;
    __syncthreads();

    f32x4 acc2 = {0.f, 0.f, 0.f, 0.f};
    for (int k = 0; k < FDIM; k += 4) {
        f32x4 xv = *(f32x4*)&h1s[g][k];
#pragma unroll
        for (int kk = 0; kk < 4; ++kk) {
            f32x4 w = *(const f32x4*)(W2 + (size_t)(k + kk) * FDIM + c4);
            acc2 += w * xv[kk];
        }
    }
    float ns = norm_s[node];
    *(f32x4*)(Y2 + ((size_t)node << 7) + c4) = acc2 * ns;
}

// ---------------- gather2: h2 = bf16( gather(y2)*nd + b2 ) ----------------
__global__ __launch_bounds__(256) void k_gat2(const float* __restrict__ Y,
                                              const int* __restrict__ row_start,
                                              const int* __restrict__ csr_src,
                                              const float* __restrict__ bias,
                                              unsigned short* __restrict__ outp) {
    int t = threadIdx.x;
    int node = blockIdx.x * 8 + (t >> 5);
    int c4 = (t & 31) << 2;
    int beg = row_start[node], end = row_start[node + 1];
    f32x4 acc0 = {0.f, 0.f, 0.f, 0.f}, acc1 = {0.f, 0.f, 0.f, 0.f};
    int e = beg;
    for (; e + 3 < end; e += 4) {
        int s0 = csr_src[e], s1 = csr_src[e + 1], s2 = csr_src[e + 2], s3 = csr_src[e + 3];
        f32x4 v0 = *(const f32x4*)(Y + ((size_t)s0 << 7) + c4);
        f32x4 v1 = *(const f32x4*)(Y + ((size_t)s1 << 7) + c4);
        f32x4 v2 = *(const f32x4*)(Y + ((size_t)s2 << 7) + c4);
        f32x4 v3 = *(const f32x4*)(Y + ((size_t)s3 << 7) + c4);
        acc0 += v0; acc1 += v1; acc0 += v2; acc1 += v3;
    }
    for (; e < end; ++e) {
        int s0 = csr_src[e];
        acc0 += *(const f32x4*)(Y + ((size_t)s0 << 7) + c4);
    }
    f32x4 acc = acc0 + acc1;
    float scale = rsqrtf(fmaxf((float)(end - beg), 1.0f));
    f32x4 b = *(const f32x4*)(bias + c4);
    f32x4 v = acc * scale + b;
    ushort4 u;
    u.x = f2bf(v[0]); u.y = f2bf(v[1]); u.z = f2bf(v[2]); u.w = f2bf(v[3]);
    *(ushort4*)(outp + ((size_t)node << 7) + c4) = u;
}

// ---------------- decode: C = sigmoid(H @ H^T), H is [8192][128] bf16 ----------------
// r10-proven optimum: LDS-staged input (XOR-swizzled), swapped-operand MFMA
// (lane-regs hold 4 consecutive cols -> float4 stores), rcp sigmoid, plain
// stores. Hypothesis sweep: no-LDS (-28us), nt-stores (-45us), transpose
// epilogue (-5us) all regressed -> this is the practical floor.
__global__ __launch_bounds__(256) void k_decode(const __hip_bfloat16* __restrict__ H,
                                                float* __restrict__ C) {
    __shared__ __align__(16) unsigned char smem[65536];
    unsigned char* sA = smem;
    unsigned char* sB = smem + 32768;
    const int ti = blockIdx.x, tj = blockIdx.y;
    const int t = threadIdx.x;
    const unsigned char* gH = (const unsigned char*)H;

#pragma unroll
    for (int i = 0; i < 8; ++i) {
        int chunk = t + i * 256;
        int row = chunk >> 4;
        int cc = (chunk & 15) << 4;
        int lofs = row * 256 + (cc ^ ((row & 7) << 4));
        *(float4*)(sA + lofs) = *(const float4*)(gH + ((size_t)(ti * 128 + row) << 8) + cc);
        *(float4*)(sB + lofs) = *(const float4*)(gH + ((size_t)(tj * 128 + row) << 8) + cc);
    }
    __syncthreads();

    const int w = t >> 6, lane = t & 63;
    const int wr = (w >> 1) * 64, wc = (w & 1) * 64;
    const int lr = lane & 15;
    const int lk = (lane >> 4) * 16;

    f32x4 acc[4][4] = {};

#pragma unroll
    for (int ks = 0; ks < 4; ++ks) {
        short8 af[4], bfr[4];
#pragma unroll
        for (int mi = 0; mi < 4; ++mi) {
            int row = wr + mi * 16 + lr;
            int off = row * 256 + ((ks * 64 + lk) ^ ((row & 7) << 4));
            af[mi] = *(const short8*)(sA + off);
        }
#pragma unroll
        for (int ni = 0; ni < 4; ++ni) {
            int row = wc + ni * 16 + lr;
            int off = row * 256 + ((ks * 64 + lk) ^ ((row & 7) << 4));
            bfr[ni] = *(const short8*)(sB + off);
        }
        // swapped operands: lane-regs hold 4 consecutive cols of one row
#pragma unroll
        for (int mi = 0; mi < 4; ++mi)
#pragma unroll
            for (int ni = 0; ni < 4; ++ni)
                acc[mi][ni] = __builtin_amdgcn_mfma_f32_16x16x32_bf16(bfr[ni], af[mi],
                                                                      acc[mi][ni], 0, 0, 0);
    }

    // lane holds: row = ti*128 + wr + mi*16 + (lane&15)
    //             cols = tj*128 + wc + ni*16 + (lane>>4)*4 + {0..3}
    const int qrow = lane & 15;
    const int pcolb = (lane >> 4) * 4;
#pragma unroll
    for (int mi = 0; mi < 4; ++mi) {
        size_t rowoff = (size_t)(ti * 128 + wr + mi * 16 + qrow) * NNODES;
#pragma unroll
        for (int ni = 0; ni < 4; ++ni) {
            int colb = tj * 128 + wc + ni * 16 + pcolb;
            f32x4 s;
#pragma unroll
            for (int r = 0; r < 4; ++r)
                s[r] = __builtin_amdgcn_rcpf(1.0f + __expf(-acc[mi][ni][r]));
            *(f32x4*)(C + rowoff + colb) = s;
        }
    }
}

extern "C" void kernel_launch(void* const* d_in, const int* in_sizes, int n_in,
                              void* d_out, int out_size, void* d_ws, size_t ws_size,
                              hipStream_t stream) {
    const float* x  = (const float*)d_in[0];
    const int* src  = (const int*)d_in[1];
    const int* dst  = (const int*)d_in[2];
    const float* W1 = (const float*)d_in[3];
    const float* b1 = (const float*)d_in[4];
    const float* W2 = (const float*)d_in[5];
    const float* b2 = (const float*)d_in[6];
    float* out = (float*)d_out;
    const int E = in_sizes[1];

    char* ws = (char*)d_ws;
    float* norm_s    = (float*)(ws + 0);                // 32KB
    int*   cnt       = (int*)(ws + (32 << 10));         // 64KB (cnt_s | cnt_d)
    int*   row_start = (int*)(ws + (96 << 10));         // 8193 ints
    int*   cursor    = (int*)(ws + (132 << 10));        // 32KB
    int*   csr_src   = (int*)(ws + (164 << 10));        // E ints = 1MB
    char*  big       = ws + (164 << 10) + ((size_t)E * 4);
    float* bufA      = (float*)big;                     // 4MB (y1)
    float* bufB      = (float*)(big + (4 << 20));       // 4MB (y2)
    __hip_bfloat16* h2bf = (__hip_bfloat16*)(big + (8 << 20));  // 2MB

    // zero degree counters (kernel, not memset — in-graph fill nodes are slow)
    k_zero<<<64, 256, 0, stream>>>(cnt, 2 * NNODES);

    // degrees, then norms + scan (single block)
    k_deg_int<<<(E + 255) / 256, 256, 0, stream>>>(src, dst, cnt, E);
    k_scan_norms<<<1, 256, 0, stream>>>(cnt, norm_s, row_start, cursor, NNODES);

    // merged: CSR fill (1024 blocks) + linear1 (512 blocks)
    const int fillB = (E + 255) / 256;
    k_fill_lin<<<fillB + NNODES / 16, 256, 0, stream>>>(src, dst, cursor, csr_src, E, fillB,
                                                        x, W1, norm_s, bufA);

    // fused: h1 = relu(gather(y1)*nd + b1) [LDS-local]; y2 = (h1@W2)*ns
    k_gatlin<<<NNODES / 8, 256, 0, stream>>>(bufA, row_start, csr_src, b1, W2, norm_s, bufB);
    // layer 2 gather: h2 = gather(y2)*nd + b2 -> bf16
    k_gat2<<<NNODES / 8, 256, 0, stream>>>(bufB, row_start, csr_src, b2, (unsigned short*)h2bf);

    // decode: out = sigmoid(h2 @ h2^T)
    k_decode<<<dim3(64, 64), 256, 0, stream>>>(h2bf, out);
}